// Round 2
// baseline (243.467 us; speedup 1.0000x reference)
//
#include <hip/hip_runtime.h>
#include <stdint.h>

// StochasticPool2d: B=16,C=96,H=W=224,K=2 -> windows 16*96*112*112 = 19,267,584
// Must bit-exactly reproduce:
//   idx = jax.random.categorical(key(42), win, axis=-1)  [threefry partitionable,
//   gumbel = -log(-log(uniform)), XLA-CPU Cephes vectorized log, argmax first-max]

#define OW 112

// ---- exact-rounding helpers: ops carry contract(off) fast-math flags so the
// backend can never fuse mul+add into FMA (XLA CPU emits separate mul/add). ----
__device__ __forceinline__ float mul_rn(float a, float b) {
#pragma clang fp contract(off)
  return a * b;
}
__device__ __forceinline__ float add_rn(float a, float b) {
#pragma clang fp contract(off)
  return a + b;
}
__device__ __forceinline__ float sub_rn(float a, float b) {
#pragma clang fp contract(off)
  return a - b;
}

// ---- XLA CPU / Eigen plog_float: Cephes log with 3-way split polynomial.
// Valid for positive, finite, normal x (all our inputs are). ----
__device__ __forceinline__ float xla_logf(float x) {
  const float SQRTHF = 0.707106781186547524f;
  uint32_t ix = __float_as_uint(x);
  float e = (float)((int)(ix >> 23) - 126);
  float m = __uint_as_float((ix & 0x007fffffu) | 0x3f000000u);  // [0.5, 1)
  // mask = m < SQRTHF; tmp = mask?m:0; m -= 1; e -= mask?1:0; m += tmp;
  if (m < SQRTHF) {
    e = sub_rn(e, 1.0f);
    m = add_rn(sub_rn(m, 1.0f), m);
  } else {
    m = sub_rn(m, 1.0f);
  }
  float z  = mul_rn(m, m);
  float x3 = mul_rn(z, m);
  float y  = add_rn(mul_rn(7.0376836292E-2f,  m), -1.1514610310E-1f);
  float y1 = add_rn(mul_rn(-1.2420140846E-1f, m),  1.4249322787E-1f);
  float y2 = add_rn(mul_rn(2.0000714765E-1f,  m), -2.4999993993E-1f);
  y  = add_rn(mul_rn(y,  m),  1.1676998740E-1f);
  y1 = add_rn(mul_rn(y1, m), -1.6668057665E-1f);
  y2 = add_rn(mul_rn(y2, m),  3.3333331174E-1f);
  y  = add_rn(mul_rn(y, x3), y1);
  y  = add_rn(mul_rn(y, x3), y2);
  y  = mul_rn(y, x3);
  y  = add_rn(mul_rn(-2.12194440e-4f, e), y);  // y += e*q1
  y  = sub_rn(y, mul_rn(z, 0.5f));             // y -= 0.5*m^2
  m  = add_rn(m, y);
  m  = add_rn(mul_rn(0.693359375f, e), m);     // m += e*q2
  return m;
}

__device__ __forceinline__ uint32_t rotl(uint32_t v, uint32_t r) {
  return (v << r) | (v >> (32u - r));
}

// threefry2x32, key=(0,42), counter words (x0,x1)=(0, idx).
// Partitionable 32-bit draw = x0_out ^ x1_out.
__device__ __forceinline__ uint32_t threefry_bits(uint32_t idx) {
  const uint32_t ks0 = 0u;
  const uint32_t ks1 = 42u;
  const uint32_t ks2 = 0x1BD11BDAu ^ 0u ^ 42u;
  uint32_t x0 = 0u + ks0;
  uint32_t x1 = idx + ks1;
#define TF_R4(a, b, c, d)                                   \
  x0 += x1; x1 = rotl(x1, a); x1 ^= x0;                     \
  x0 += x1; x1 = rotl(x1, b); x1 ^= x0;                     \
  x0 += x1; x1 = rotl(x1, c); x1 ^= x0;                     \
  x0 += x1; x1 = rotl(x1, d); x1 ^= x0;
  TF_R4(13, 15, 26, 6)
  x0 += ks1; x1 += ks2 + 1u;
  TF_R4(17, 29, 16, 24)
  x0 += ks2; x1 += ks0 + 2u;
  TF_R4(13, 15, 26, 6)
  x0 += ks0; x1 += ks1 + 3u;
  TF_R4(17, 29, 16, 24)
  x0 += ks1; x1 += ks2 + 4u;
  TF_R4(13, 15, 26, 6)
  x0 += ks2; x1 += ks0 + 5u;
#undef TF_R4
  return x0 ^ x1;
}

// uniform in [tiny, 1) then gumbel = -log(-log(u)), all per XLA f32 semantics.
__device__ __forceinline__ float gumbel_from_idx(uint32_t idx) {
  uint32_t bits = threefry_bits(idx);
  float f = sub_rn(__uint_as_float((bits >> 9) | 0x3f800000u), 1.0f);  // [0,1)
  float u = fmaxf(1.17549435082228751e-38f, f);  // f*(1-tiny)+tiny == f exactly
  float w = -xla_logf(u);   // fneg is exact
  return -xla_logf(w);
}

extern "C" __global__ void __launch_bounds__(256)
stochpool_kernel(const float* __restrict__ x, float* __restrict__ out, int nwin) {
  int tid = blockIdx.x * 256 + threadIdx.x;
  if (tid >= nwin) return;
  // tid = ((b*C + c)*oh + i)*ow + j
  uint32_t ut = (uint32_t)tid;
  uint32_t j  = ut % OW;
  uint32_t r  = ut / OW;
  uint32_t i  = r % OW;       // oh == ow == 112
  uint32_t bc = r / OW;
  const float* base = x + ((size_t)bc * 224u + (size_t)(2u * i)) * 224u + 2u * j;
  float2 r0 = *reinterpret_cast<const float2*>(base);
  float2 r1 = *reinterpret_cast<const float2*>(base + 224);
  float w0 = r0.x, w1 = r0.y, w2 = r1.x, w3 = r1.y;

  uint32_t n = ut * 4u;  // flat gumbel index over (B,C,oh,ow,4)
  float s0 = add_rn(gumbel_from_idx(n + 0u), w0);
  float s1 = add_rn(gumbel_from_idx(n + 1u), w1);
  float s2 = add_rn(gumbel_from_idx(n + 2u), w2);
  float s3 = add_rn(gumbel_from_idx(n + 3u), w3);

  // argmax, first-max-wins (matches jnp.argmax tie-breaking)
  float best = s0, val = w0;
  if (s1 > best) { best = s1; val = w1; }
  if (s2 > best) { best = s2; val = w2; }
  if (s3 > best) { best = s3; val = w3; }
  out[tid] = val;
}

extern "C" void kernel_launch(void* const* d_in, const int* in_sizes, int n_in,
                              void* d_out, int out_size, void* d_ws, size_t ws_size,
                              hipStream_t stream) {
  const float* x = (const float*)d_in[0];
  float* out = (float*)d_out;
  int nwin = out_size;  // 19,267,584
  int blocks = (nwin + 255) / 256;
  stochpool_kernel<<<blocks, 256, 0, stream>>>(x, out, nwin);
}

// Round 3
// 233.310 us; speedup vs baseline: 1.0435x; 1.0435x over previous
//
#include <hip/hip_runtime.h>
#include <stdint.h>

// StochasticPool2d: B=16,C=96,H=W=224,K=2 -> windows 16*96*112*112 = 19,267,584
// Bit-exact reproduction of:
//   idx = jax.random.categorical(key(42), win, axis=-1)  [threefry partitionable,
//   gumbel = -log(-log(uniform)), XLA-CPU Cephes/Eigen plog, argmax first-max]
// Round-2 version passed with absmax 0.0; this round is VALU-throughput tuning
// with numerically identical operations:
//   - branchless Cephes log (cndmask instead of divergent branch)
//   - __builtin_rotateleft32 -> guaranteed v_alignbit_b32
//   - 2 windows/thread: float4 loads, float2 stores, amortized index math

#define OW  112
#define OWH 56

// ---- exact-rounding helpers: contract(off) so mul+add never fuse into FMA
// (XLA CPU emits separate mul/add). ----
__device__ __forceinline__ float mul_rn(float a, float b) {
#pragma clang fp contract(off)
  return a * b;
}
__device__ __forceinline__ float add_rn(float a, float b) {
#pragma clang fp contract(off)
  return a + b;
}
__device__ __forceinline__ float sub_rn(float a, float b) {
#pragma clang fp contract(off)
  return a - b;
}

// ---- XLA CPU / Eigen plog_float (Cephes), branchless.
// Select arms are the exact computations of the round-2 version:
//   c: m' = (m-1)+m, e' = e-1   |   !c: m' = m-1, e' = e
// (m-1) is exact by Sterbenz, so both arms round identically to round 2. ----
__device__ __forceinline__ float xla_logf(float x) {
  uint32_t ix = __float_as_uint(x);
  float e = (float)((int)(ix >> 23) - 126);
  float m = __uint_as_float((ix & 0x007fffffu) | 0x3f000000u);  // [0.5, 1)
  bool c = m < 0.707106781186547524f;
  float mm1 = sub_rn(m, 1.0f);
  m = c ? add_rn(mm1, m) : mm1;
  e = c ? sub_rn(e, 1.0f) : e;
  float z  = mul_rn(m, m);
  float x3 = mul_rn(z, m);
  float y  = add_rn(mul_rn(7.0376836292E-2f,  m), -1.1514610310E-1f);
  float y1 = add_rn(mul_rn(-1.2420140846E-1f, m),  1.4249322787E-1f);
  float y2 = add_rn(mul_rn(2.0000714765E-1f,  m), -2.4999993993E-1f);
  y  = add_rn(mul_rn(y,  m),  1.1676998740E-1f);
  y1 = add_rn(mul_rn(y1, m), -1.6668057665E-1f);
  y2 = add_rn(mul_rn(y2, m),  3.3333331174E-1f);
  y  = add_rn(mul_rn(y, x3), y1);
  y  = add_rn(mul_rn(y, x3), y2);
  y  = mul_rn(y, x3);
  y  = add_rn(mul_rn(-2.12194440e-4f, e), y);  // y += e*q1
  y  = sub_rn(y, mul_rn(z, 0.5f));             // y -= 0.5*m^2
  m  = add_rn(m, y);
  m  = add_rn(mul_rn(0.693359375f, e), m);     // m += e*q2
  return m;
}

// threefry2x32, key=(0,42), counter (0, idx); partitionable draw = x0 ^ x1.
__device__ __forceinline__ uint32_t threefry_bits(uint32_t idx) {
  const uint32_t ks0 = 0u;
  const uint32_t ks1 = 42u;
  const uint32_t ks2 = 0x1BD11BDAu ^ 0u ^ 42u;
  uint32_t x0 = 0u + ks0;
  uint32_t x1 = idx + ks1;
#define TF_R4(a, b, c, d)                                           \
  x0 += x1; x1 = __builtin_rotateleft32(x1, a); x1 ^= x0;           \
  x0 += x1; x1 = __builtin_rotateleft32(x1, b); x1 ^= x0;           \
  x0 += x1; x1 = __builtin_rotateleft32(x1, c); x1 ^= x0;           \
  x0 += x1; x1 = __builtin_rotateleft32(x1, d); x1 ^= x0;
  TF_R4(13u, 15u, 26u, 6u)
  x0 += ks1; x1 += ks2 + 1u;
  TF_R4(17u, 29u, 16u, 24u)
  x0 += ks2; x1 += ks0 + 2u;
  TF_R4(13u, 15u, 26u, 6u)
  x0 += ks0; x1 += ks1 + 3u;
  TF_R4(17u, 29u, 16u, 24u)
  x0 += ks1; x1 += ks2 + 4u;
  TF_R4(13u, 15u, 26u, 6u)
  x0 += ks2; x1 += ks0 + 5u;
#undef TF_R4
  return x0 ^ x1;
}

// -log(u) for draw idx; caller applies the second log and its negation.
__device__ __forceinline__ float neglog_u(uint32_t idx) {
  uint32_t bits = threefry_bits(idx);
  float f = sub_rn(__uint_as_float((bits >> 9) | 0x3f800000u), 1.0f);  // [0,1)
  float u = fmaxf(1.17549435082228751e-38f, f);  // == f*(1-tiny)+tiny exactly
  return -xla_logf(u);
}

// One 2x2 window: values w0..w3, gumbel counter base n. Returns selected value.
// s_k = w_k + (-log(-log u_k)) computed as sub_rn(w_k, log(...)), bit-identical
// to add_rn(-log(...), w_k).
__device__ __forceinline__ float pool_window(float w0, float w1, float w2,
                                             float w3, uint32_t n) {
  float s0 = sub_rn(w0, xla_logf(neglog_u(n + 0u)));
  float s1 = sub_rn(w1, xla_logf(neglog_u(n + 1u)));
  float s2 = sub_rn(w2, xla_logf(neglog_u(n + 2u)));
  float s3 = sub_rn(w3, xla_logf(neglog_u(n + 3u)));
  // argmax, first-max-wins (jnp.argmax tie-breaking)
  float best = s0, val = w0;
  if (s1 > best) { best = s1; val = w1; }
  if (s2 > best) { best = s2; val = w2; }
  if (s3 > best) { best = s3; val = w3; }
  return val;
}

extern "C" __global__ void __launch_bounds__(256)
stochpool_kernel(const float* __restrict__ x, float* __restrict__ out,
                 int nhalf) {
  int t = blockIdx.x * 256 + threadIdx.x;
  if (t >= nhalf) return;
  // t = (bc*112 + i)*56 + jh ; window pair at j = 2*jh, j+1
  uint32_t ut = (uint32_t)t;
  uint32_t jh = ut % OWH;
  uint32_t r  = ut / OWH;        // bc*112 + i
  uint32_t i  = r % OW;
  uint32_t bc = r / OW;
  uint32_t j  = jh * 2u;

  const float* base = x + ((size_t)bc * 224u + (size_t)(2u * i)) * 224u + 2u * j;
  float4 r0 = *reinterpret_cast<const float4*>(base);        // 16B aligned
  float4 r1 = *reinterpret_cast<const float4*>(base + 224);  // 896B offset, aligned

  uint32_t wid = r * OW + j;     // flat window index (== output index)
  float oA = pool_window(r0.x, r0.y, r1.x, r1.y, wid * 4u);
  float oB = pool_window(r0.z, r0.w, r1.z, r1.w, (wid + 1u) * 4u);

  *reinterpret_cast<float2*>(out + wid) = make_float2(oA, oB);  // 8B aligned
}

extern "C" void kernel_launch(void* const* d_in, const int* in_sizes, int n_in,
                              void* d_out, int out_size, void* d_ws, size_t ws_size,
                              hipStream_t stream) {
  const float* x = (const float*)d_in[0];
  float* out = (float*)d_out;
  int nhalf = out_size / 2;  // 9,633,792 window-pairs
  int blocks = (nhalf + 255) / 256;
  stochpool_kernel<<<blocks, 256, 0, stream>>>(x, out, nhalf);
}

// Round 4
// 231.869 us; speedup vs baseline: 1.0500x; 1.0062x over previous
//
#include <hip/hip_runtime.h>
#include <stdint.h>

// StochasticPool2d: B=16,C=96,H=W=224,K=2 -> windows 16*96*112*112 = 19,267,584
// Bit-exact reproduction of:
//   idx = jax.random.categorical(key(42), win, axis=-1)  [threefry partitionable,
//   gumbel = -log(-log(uniform)), XLA-CPU Cephes/Eigen plog, argmax first-max]
// Rounds 2-3 passed absmax 0.0. This round: identical arithmetic, fewer VALU
// issues -- packed fp32 (v_pk_mul_f32/v_pk_add_f32, IEEE per-half, bit-exact)
// for the 8 Cephes logs per window, and 4 windows/thread.

#define OW 112

typedef float    v2f __attribute__((ext_vector_type(2)));
typedef uint32_t v2u __attribute__((ext_vector_type(2)));
typedef int32_t  v2i __attribute__((ext_vector_type(2)));

// ---- exact-rounding packed helpers: contract(off) so mul+add never fuse ----
__device__ __forceinline__ v2f pmul(v2f a, v2f b) {
#pragma clang fp contract(off)
  return a * b;
}
__device__ __forceinline__ v2f padd(v2f a, v2f b) {
#pragma clang fp contract(off)
  return a + b;
}
__device__ __forceinline__ v2f psub(v2f a, v2f b) {
#pragma clang fp contract(off)
  return a - b;
}
__device__ __forceinline__ float sub_rn(float a, float b) {
#pragma clang fp contract(off)
  return a - b;
}
__device__ __forceinline__ v2f splat(float s) { v2f r; r.x = s; r.y = s; return r; }

// ---- XLA CPU / Eigen plog_float (Cephes), packed 2-wide, branchless.
// Per-lane op sequence identical to the round-2/3 scalar version. ----
__device__ __forceinline__ v2f xla_logf2(v2f x) {
  v2u ix = __builtin_bit_cast(v2u, x);
  v2f e = __builtin_convertvector(__builtin_bit_cast(v2i, ix >> 23), v2f);
  e = psub(e, splat(126.0f));  // exact: small integers
  v2f m = __builtin_bit_cast(v2f, (ix & 0x007fffffu) | 0x3f000000u);  // [0.5,1)
  bool c0 = m.x < 0.707106781186547524f;
  bool c1 = m.y < 0.707106781186547524f;
  v2f mm1 = psub(m, splat(1.0f));   // exact (Sterbenz)
  v2f m2  = padd(mm1, m);
  m.x = c0 ? m2.x : mm1.x;
  m.y = c1 ? m2.y : mm1.y;
  e.x = c0 ? sub_rn(e.x, 1.0f) : e.x;
  e.y = c1 ? sub_rn(e.y, 1.0f) : e.y;
  v2f z  = pmul(m, m);
  v2f x3 = pmul(z, m);
  v2f y  = padd(pmul(splat(7.0376836292E-2f),  m), splat(-1.1514610310E-1f));
  v2f y1 = padd(pmul(splat(-1.2420140846E-1f), m), splat( 1.4249322787E-1f));
  v2f y2 = padd(pmul(splat(2.0000714765E-1f),  m), splat(-2.4999993993E-1f));
  y  = padd(pmul(y,  m), splat( 1.1676998740E-1f));
  y1 = padd(pmul(y1, m), splat(-1.6668057665E-1f));
  y2 = padd(pmul(y2, m), splat( 3.3333331174E-1f));
  y  = padd(pmul(y, x3), y1);
  y  = padd(pmul(y, x3), y2);
  y  = pmul(y, x3);
  y  = padd(pmul(splat(-2.12194440e-4f), e), y);  // y += e*q1
  y  = psub(y, pmul(z, splat(0.5f)));             // y -= 0.5*m^2
  m  = padd(m, y);
  m  = padd(pmul(splat(0.693359375f), e), m);     // m += e*q2
  return m;
}

// threefry2x32, key=(0,42), counter (0, idx); partitionable draw = x0 ^ x1.
__device__ __forceinline__ uint32_t threefry_bits(uint32_t idx) {
  const uint32_t ks0 = 0u;
  const uint32_t ks1 = 42u;
  const uint32_t ks2 = 0x1BD11BDAu ^ 0u ^ 42u;
  uint32_t x0 = 0u + ks0;
  uint32_t x1 = idx + ks1;
#define TF_R4(a, b, c, d)                                           \
  x0 += x1; x1 = __builtin_rotateleft32(x1, a); x1 ^= x0;           \
  x0 += x1; x1 = __builtin_rotateleft32(x1, b); x1 ^= x0;           \
  x0 += x1; x1 = __builtin_rotateleft32(x1, c); x1 ^= x0;           \
  x0 += x1; x1 = __builtin_rotateleft32(x1, d); x1 ^= x0;
  TF_R4(13u, 15u, 26u, 6u)
  x0 += ks1; x1 += ks2 + 1u;
  TF_R4(17u, 29u, 16u, 24u)
  x0 += ks2; x1 += ks0 + 2u;
  TF_R4(13u, 15u, 26u, 6u)
  x0 += ks0; x1 += ks1 + 3u;
  TF_R4(17u, 29u, 16u, 24u)
  x0 += ks1; x1 += ks2 + 4u;
  TF_R4(13u, 15u, 26u, 6u)
  x0 += ks2; x1 += ks0 + 5u;
#undef TF_R4
  return x0 ^ x1;
}

// log(-log(u)) for draws (n0, n1), packed. Gumbel = -(returned value);
// caller folds the negation into the score subtract (bit-exact).
__device__ __forceinline__ v2f loglogu_pair(uint32_t n0, uint32_t n1) {
  uint32_t b0 = threefry_bits(n0);
  uint32_t b1 = threefry_bits(n1);
  v2f fb;
  fb.x = __uint_as_float((b0 >> 9) | 0x3f800000u);
  fb.y = __uint_as_float((b1 >> 9) | 0x3f800000u);
  v2f f = psub(fb, splat(1.0f));                    // [0,1)
  v2f u;
  u.x = fmaxf(1.17549435082228751e-38f, f.x);       // == f*(1-tiny)+tiny exactly
  u.y = fmaxf(1.17549435082228751e-38f, f.y);
  v2f lu = xla_logf2(u);
  v2f w;
  w.x = -lu.x;  // exact sign flip
  w.y = -lu.y;
  return xla_logf2(w);
}

// One 2x2 window: s_k = w_k - log(-log u_k)  (== w_k + gumbel_k bitwise).
__device__ __forceinline__ float pool_window(float w0, float w1, float w2,
                                             float w3, uint32_t n) {
  v2f lA = loglogu_pair(n + 0u, n + 1u);
  v2f lB = loglogu_pair(n + 2u, n + 3u);
  v2f wA; wA.x = w0; wA.y = w1;
  v2f wB; wB.x = w2; wB.y = w3;
  v2f sA = psub(wA, lA);
  v2f sB = psub(wB, lB);
  // argmax, first-max-wins (jnp.argmax tie-breaking)
  float best = sA.x, val = w0;
  if (sA.y > best) { best = sA.y; val = w1; }
  if (sB.x > best) { best = sB.x; val = w2; }
  if (sB.y > best) { best = sB.y; val = w3; }
  return val;
}

extern "C" __global__ void __launch_bounds__(256)
stochpool_kernel(const float* __restrict__ x, float* __restrict__ out,
                 int nquad) {
  int t = blockIdx.x * 256 + threadIdx.x;
  if (t >= nquad) return;
  // t = (bc*112 + i)*28 + jq ; 4 windows at j = 4*jq .. 4*jq+3
  uint32_t ut = (uint32_t)t;
  uint32_t jq = ut % 28u;
  uint32_t r  = ut / 28u;        // bc*112 + i
  uint32_t i  = r % OW;
  uint32_t bc = r / OW;
  uint32_t j  = jq * 4u;

  const float* base =
      x + ((size_t)bc * 224u + (size_t)(2u * i)) * 224u + 2u * j;
  float4 a0 = *reinterpret_cast<const float4*>(base);
  float4 a1 = *reinterpret_cast<const float4*>(base + 4);
  float4 b0 = *reinterpret_cast<const float4*>(base + 224);
  float4 b1 = *reinterpret_cast<const float4*>(base + 228);

  uint32_t wid = r * OW + j;     // flat window index (== output index, %4==0)
  float o0 = pool_window(a0.x, a0.y, b0.x, b0.y, (wid + 0u) * 4u);
  float o1 = pool_window(a0.z, a0.w, b0.z, b0.w, (wid + 1u) * 4u);
  float o2 = pool_window(a1.x, a1.y, b1.x, b1.y, (wid + 2u) * 4u);
  float o3 = pool_window(a1.z, a1.w, b1.z, b1.w, (wid + 3u) * 4u);

  *reinterpret_cast<float4*>(out + wid) = make_float4(o0, o1, o2, o3);
}

extern "C" void kernel_launch(void* const* d_in, const int* in_sizes, int n_in,
                              void* d_out, int out_size, void* d_ws, size_t ws_size,
                              hipStream_t stream) {
  const float* x = (const float*)d_in[0];
  float* out = (float*)d_out;
  int nquad = out_size / 4;  // 4,816,896 window-quads
  int blocks = (nquad + 255) / 256;
  stochpool_kernel<<<blocks, 256, 0, stream>>>(x, out, nquad);
}

// Round 5
// 154.523 us; speedup vs baseline: 1.5756x; 1.5005x over previous
//
#include <hip/hip_runtime.h>
#include <stdint.h>

// StochasticPool2d: B=16,C=96,H=W=224,K=2 -> windows 16*96*112*112 = 19,267,584
// Bit-exact reproduction of:
//   idx = jax.random.categorical(key(42), win, axis=-1)  [threefry partitionable,
//   gumbel = -log(-log(uniform)), XLA-CPU Cephes/Eigen plog, argmax first-max]
// Rounds 2-4 passed absmax 0.0 (exact Cephes everywhere, ~232 us, VALU-bound).
// This round: fast path computes gumbels with v_log_f32 (1 ULP) and takes the
// window's argmax only when the top-2 margin exceeds ETA=2e-4 (>>12x the
// worst-case |fast - exact| error bound ~8e-6, so the exact argmax provably
// matches). Sub-margin windows (~1e-4 of all) fall back to the exact Cephes
// path, reusing the threefry bits. Output value is a bit-exact input copy.

#define OW 112

// ---- exact-rounding helpers: contract(off) so mul+add never fuse into FMA
// (XLA CPU emits separate mul/add). Used by the exact fallback path. ----
__device__ __forceinline__ float mul_rn(float a, float b) {
#pragma clang fp contract(off)
  return a * b;
}
__device__ __forceinline__ float add_rn(float a, float b) {
#pragma clang fp contract(off)
  return a + b;
}
__device__ __forceinline__ float sub_rn(float a, float b) {
#pragma clang fp contract(off)
  return a - b;
}

// ---- XLA CPU / Eigen plog_float (Cephes), branchless, bit-exact (verified
// absmax 0.0 in rounds 2-4). ----
__device__ __forceinline__ float xla_logf(float x) {
  uint32_t ix = __float_as_uint(x);
  float e = (float)((int)(ix >> 23) - 126);
  float m = __uint_as_float((ix & 0x007fffffu) | 0x3f000000u);  // [0.5, 1)
  bool c = m < 0.707106781186547524f;
  float mm1 = sub_rn(m, 1.0f);   // exact (Sterbenz)
  m = c ? add_rn(mm1, m) : mm1;
  e = c ? sub_rn(e, 1.0f) : e;
  float z  = mul_rn(m, m);
  float x3 = mul_rn(z, m);
  float y  = add_rn(mul_rn(7.0376836292E-2f,  m), -1.1514610310E-1f);
  float y1 = add_rn(mul_rn(-1.2420140846E-1f, m),  1.4249322787E-1f);
  float y2 = add_rn(mul_rn(2.0000714765E-1f,  m), -2.4999993993E-1f);
  y  = add_rn(mul_rn(y,  m),  1.1676998740E-1f);
  y1 = add_rn(mul_rn(y1, m), -1.6668057665E-1f);
  y2 = add_rn(mul_rn(y2, m),  3.3333331174E-1f);
  y  = add_rn(mul_rn(y, x3), y1);
  y  = add_rn(mul_rn(y, x3), y2);
  y  = mul_rn(y, x3);
  y  = add_rn(mul_rn(-2.12194440e-4f, e), y);  // y += e*q1
  y  = sub_rn(y, mul_rn(z, 0.5f));             // y -= 0.5*m^2
  m  = add_rn(m, y);
  m  = add_rn(mul_rn(0.693359375f, e), m);     // m += e*q2
  return m;
}

// threefry2x32, key=(0,42), counter (0, idx); partitionable draw = x0 ^ x1.
__device__ __forceinline__ uint32_t threefry_bits(uint32_t idx) {
  const uint32_t ks0 = 0u;
  const uint32_t ks1 = 42u;
  const uint32_t ks2 = 0x1BD11BDAu ^ 0u ^ 42u;
  uint32_t x0 = 0u + ks0;
  uint32_t x1 = idx + ks1;
#define TF_R4(a, b, c, d)                                           \
  x0 += x1; x1 = __builtin_rotateleft32(x1, a); x1 ^= x0;           \
  x0 += x1; x1 = __builtin_rotateleft32(x1, b); x1 ^= x0;           \
  x0 += x1; x1 = __builtin_rotateleft32(x1, c); x1 ^= x0;           \
  x0 += x1; x1 = __builtin_rotateleft32(x1, d); x1 ^= x0;
  TF_R4(13u, 15u, 26u, 6u)
  x0 += ks1; x1 += ks2 + 1u;
  TF_R4(17u, 29u, 16u, 24u)
  x0 += ks2; x1 += ks0 + 2u;
  TF_R4(13u, 15u, 26u, 6u)
  x0 += ks0; x1 += ks1 + 3u;
  TF_R4(17u, 29u, 16u, 24u)
  x0 += ks1; x1 += ks2 + 4u;
  TF_R4(13u, 15u, 26u, 6u)
  x0 += ks2; x1 += ks0 + 5u;
#undef TF_R4
  return x0 ^ x1;
}

// uniform u in [tiny,1) from draw bits (exact, shared by both paths)
__device__ __forceinline__ float uniform_from_bits(uint32_t bits) {
  float f = sub_rn(__uint_as_float((bits >> 9) | 0x3f800000u), 1.0f);  // exact
  return fmaxf(1.17549435082228751e-38f, f);  // == f*(1-tiny)+tiny exactly
}

// fast gumbel: -ln(-ln u) via v_log_f32 (log2) * -ln2. |err| <= ~4e-6 abs.
__device__ __forceinline__ float fast_gumbel(uint32_t bits) {
  const float NLN2 = -0.69314718055994530942f;
  float u = uniform_from_bits(bits);
  float w = __builtin_amdgcn_logf(u) * NLN2;   // ~= -ln u  (>0, normal range)
  return __builtin_amdgcn_logf(w) * NLN2;      // ~= -ln(-ln u)
}

// exact score: s = w_val - log(-log u), the exact round-2/3 sequence.
__device__ __forceinline__ float exact_score(float wval, uint32_t bits) {
  float u = uniform_from_bits(bits);
  float nlu = -xla_logf(u);       // exact sign flip
  return sub_rn(wval, xla_logf(nlu));
}

// One 2x2 window. Fast scores + margin test; exact fallback when ambiguous.
__device__ __forceinline__ float pool_window(float w0, float w1, float w2,
                                             float w3, uint32_t n) {
  uint32_t b0 = threefry_bits(n + 0u);
  uint32_t b1 = threefry_bits(n + 1u);
  uint32_t b2 = threefry_bits(n + 2u);
  uint32_t b3 = threefry_bits(n + 3u);

  float s0 = w0 + fast_gumbel(b0);
  float s1 = w1 + fast_gumbel(b1);
  float s2 = w2 + fast_gumbel(b2);
  float s3 = w3 + fast_gumbel(b3);

  // argmax, first-max-wins
  float best = s0, val = w0;
  if (s1 > best) { best = s1; val = w1; }
  if (s2 > best) { best = s2; val = w2; }
  if (s3 > best) { best = s3; val = w3; }

  // top-2 margin: hi - sec
  float h01 = fmaxf(s0, s1), l01 = fminf(s0, s1);
  float h23 = fmaxf(s2, s3), l23 = fminf(s2, s3);
  float hi  = fmaxf(h01, h23);
  float sec = fmaxf(fminf(h01, h23), fmaxf(l01, l23));
  if (hi - sec > 2e-4f) return val;   // provably same argmax as exact path

  // exact fallback (rare: ~1e-4 of windows); reuses threefry bits
  float e0 = exact_score(w0, b0);
  float e1 = exact_score(w1, b1);
  float e2 = exact_score(w2, b2);
  float e3 = exact_score(w3, b3);
  float ebest = e0; val = w0;
  if (e1 > ebest) { ebest = e1; val = w1; }
  if (e2 > ebest) { ebest = e2; val = w2; }
  if (e3 > ebest) { ebest = e3; val = w3; }
  return val;
}

extern "C" __global__ void __launch_bounds__(256)
stochpool_kernel(const float* __restrict__ x, float* __restrict__ out,
                 int nquad) {
  int t = blockIdx.x * 256 + threadIdx.x;
  if (t >= nquad) return;
  // t = (bc*112 + i)*28 + jq ; 4 windows at j = 4*jq .. 4*jq+3
  uint32_t ut = (uint32_t)t;
  uint32_t jq = ut % 28u;
  uint32_t r  = ut / 28u;        // bc*112 + i
  uint32_t i  = r % OW;
  uint32_t bc = r / OW;
  uint32_t j  = jq * 4u;

  const float* base =
      x + ((size_t)bc * 224u + (size_t)(2u * i)) * 224u + 2u * j;
  float4 a0 = *reinterpret_cast<const float4*>(base);
  float4 a1 = *reinterpret_cast<const float4*>(base + 4);
  float4 b0 = *reinterpret_cast<const float4*>(base + 224);
  float4 b1 = *reinterpret_cast<const float4*>(base + 228);

  uint32_t wid = r * OW + j;     // flat window index (== output index, %4==0)
  float o0 = pool_window(a0.x, a0.y, b0.x, b0.y, (wid + 0u) * 4u);
  float o1 = pool_window(a0.z, a0.w, b0.z, b0.w, (wid + 1u) * 4u);
  float o2 = pool_window(a1.x, a1.y, b1.x, b1.y, (wid + 2u) * 4u);
  float o3 = pool_window(a1.z, a1.w, b1.z, b1.w, (wid + 3u) * 4u);

  *reinterpret_cast<float4*>(out + wid) = make_float4(o0, o1, o2, o3);
}

extern "C" void kernel_launch(void* const* d_in, const int* in_sizes, int n_in,
                              void* d_out, int out_size, void* d_ws, size_t ws_size,
                              hipStream_t stream) {
  const float* x = (const float*)d_in[0];
  float* out = (float*)d_out;
  int nquad = out_size / 4;  // 4,816,896 window-quads
  int blocks = (nquad + 255) / 256;
  stochpool_kernel<<<blocks, 256, 0, stream>>>(x, out, nquad);
}

// Round 6
// 152.351 us; speedup vs baseline: 1.5981x; 1.0143x over previous
//
#include <hip/hip_runtime.h>
#include <stdint.h>

// StochasticPool2d: B=16,C=96,H=W=224,K=2 -> windows 16*96*112*112 = 19,267,584
// Bit-exact reproduction of:
//   idx = jax.random.categorical(key(42), win, axis=-1)  [threefry partitionable,
//   gumbel = -log(-log(uniform)), XLA-CPU Cephes/Eigen plog, argmax first-max]
// R2-R4: exact Cephes everywhere (232 us). R5: v_log_f32 fast path + margin
// test + exact Cephes fallback (154.5 us, absmax 0.0). This round: certified
// micro-trims only -- alignbit uniform construction (bit-identical), fma fast
// scores (covered by margin ETA), tournament argmax (provably equivalent).
// Threefry (280 lane-ops/window) is at its ISA floor and dominates (76%).

#define OW 112

// ---- exact-rounding helpers: contract(off) so mul+add never fuse into FMA
// (XLA CPU emits separate mul/add). Used by the exact fallback path. ----
__device__ __forceinline__ float mul_rn(float a, float b) {
#pragma clang fp contract(off)
  return a * b;
}
__device__ __forceinline__ float add_rn(float a, float b) {
#pragma clang fp contract(off)
  return a + b;
}
__device__ __forceinline__ float sub_rn(float a, float b) {
#pragma clang fp contract(off)
  return a - b;
}

// ---- XLA CPU / Eigen plog_float (Cephes), branchless, bit-exact (verified
// absmax 0.0 in rounds 2-5). ----
__device__ __forceinline__ float xla_logf(float x) {
  uint32_t ix = __float_as_uint(x);
  float e = (float)((int)(ix >> 23) - 126);
  float m = __uint_as_float((ix & 0x007fffffu) | 0x3f000000u);  // [0.5, 1)
  bool c = m < 0.707106781186547524f;
  float mm1 = sub_rn(m, 1.0f);   // exact (Sterbenz)
  m = c ? add_rn(mm1, m) : mm1;
  e = c ? sub_rn(e, 1.0f) : e;
  float z  = mul_rn(m, m);
  float x3 = mul_rn(z, m);
  float y  = add_rn(mul_rn(7.0376836292E-2f,  m), -1.1514610310E-1f);
  float y1 = add_rn(mul_rn(-1.2420140846E-1f, m),  1.4249322787E-1f);
  float y2 = add_rn(mul_rn(2.0000714765E-1f,  m), -2.4999993993E-1f);
  y  = add_rn(mul_rn(y,  m),  1.1676998740E-1f);
  y1 = add_rn(mul_rn(y1, m), -1.6668057665E-1f);
  y2 = add_rn(mul_rn(y2, m),  3.3333331174E-1f);
  y  = add_rn(mul_rn(y, x3), y1);
  y  = add_rn(mul_rn(y, x3), y2);
  y  = mul_rn(y, x3);
  y  = add_rn(mul_rn(-2.12194440e-4f, e), y);  // y += e*q1
  y  = sub_rn(y, mul_rn(z, 0.5f));             // y -= 0.5*m^2
  m  = add_rn(m, y);
  m  = add_rn(mul_rn(0.693359375f, e), m);     // m += e*q2
  return m;
}

// threefry2x32, key=(0,42), counter (0, idx); partitionable draw = x0 ^ x1.
__device__ __forceinline__ uint32_t threefry_bits(uint32_t idx) {
  const uint32_t ks0 = 0u;
  const uint32_t ks1 = 42u;
  const uint32_t ks2 = 0x1BD11BDAu ^ 0u ^ 42u;
  uint32_t x0 = 0u + ks0;
  uint32_t x1 = idx + ks1;
#define TF_R4(a, b, c, d)                                           \
  x0 += x1; x1 = __builtin_rotateleft32(x1, a); x1 ^= x0;           \
  x0 += x1; x1 = __builtin_rotateleft32(x1, b); x1 ^= x0;           \
  x0 += x1; x1 = __builtin_rotateleft32(x1, c); x1 ^= x0;           \
  x0 += x1; x1 = __builtin_rotateleft32(x1, d); x1 ^= x0;
  TF_R4(13u, 15u, 26u, 6u)
  x0 += ks1; x1 += ks2 + 1u;
  TF_R4(17u, 29u, 16u, 24u)
  x0 += ks2; x1 += ks0 + 2u;
  TF_R4(13u, 15u, 26u, 6u)
  x0 += ks0; x1 += ks1 + 3u;
  TF_R4(17u, 29u, 16u, 24u)
  x0 += ks1; x1 += ks2 + 4u;
  TF_R4(13u, 15u, 26u, 6u)
  x0 += ks2; x1 += ks0 + 5u;
#undef TF_R4
  return x0 ^ x1;
}

// uniform u in [tiny,1) from draw bits (exact, shared by both paths).
// alignbit(127, bits, 9) == (127<<23) | (bits>>9) == (bits>>9) | 0x3f800000.
__device__ __forceinline__ float uniform_from_bits(uint32_t bits) {
  uint32_t fb = __builtin_amdgcn_alignbit(127u, bits, 9u);
  float f = sub_rn(__uint_as_float(fb), 1.0f);   // exact
  return fmaxf(1.17549435082228751e-38f, f);     // == f*(1-tiny)+tiny exactly
}

// fast score: w + (-ln(-ln u)) via v_log_f32 (1 ULP). |err vs exact| <= ~8e-6.
__device__ __forceinline__ float fast_score(float wval, uint32_t bits) {
  const float NLN2 = -0.69314718055994530942f;
  float u = uniform_from_bits(bits);
  float w = __builtin_amdgcn_logf(u) * NLN2;           // ~= -ln u  (>= 0)
  return fmaf(NLN2, __builtin_amdgcn_logf(w), wval);   // w + -ln(w)
}

// exact score: s = w_val - log(-log u), the exact round-2/3 sequence.
__device__ __forceinline__ float exact_score(float wval, uint32_t bits) {
  float u = uniform_from_bits(bits);
  float nlu = -xla_logf(u);       // exact sign flip
  return sub_rn(wval, xla_logf(nlu));
}

// One 2x2 window. Fast scores + margin test; exact fallback when ambiguous.
__device__ __forceinline__ float pool_window(float w0, float w1, float w2,
                                             float w3, uint32_t n) {
  uint32_t b0 = threefry_bits(n + 0u);
  uint32_t b1 = threefry_bits(n + 1u);
  uint32_t b2 = threefry_bits(n + 2u);
  uint32_t b3 = threefry_bits(n + 3u);

  float s0 = fast_score(w0, b0);
  float s1 = fast_score(w1, b1);
  float s2 = fast_score(w2, b2);
  float s3 = fast_score(w3, b3);

  // tournament argmax, first-max-wins (ties resolve to earlier index):
  float h01 = fmaxf(s0, s1);
  float v01 = (s1 > s0) ? w1 : w0;
  float h23 = fmaxf(s2, s3);
  float v23 = (s3 > s2) ? w3 : w2;
  float hi  = fmaxf(h01, h23);
  float val = (h23 > h01) ? v23 : v01;
  // second-max of four: max(min of pair-winners, max of pair-losers)
  float sec = fmaxf(fminf(h01, h23), fmaxf(fminf(s0, s1), fminf(s2, s3)));
  if (hi - sec > 2e-4f) return val;   // provably same argmax as exact path

  // exact fallback (rare: ~1e-4 of windows); reuses threefry bits
  float e0 = exact_score(w0, b0);
  float e1 = exact_score(w1, b1);
  float e2 = exact_score(w2, b2);
  float e3 = exact_score(w3, b3);
  float ebest = e0; val = w0;
  if (e1 > ebest) { ebest = e1; val = w1; }
  if (e2 > ebest) { ebest = e2; val = w2; }
  if (e3 > ebest) { ebest = e3; val = w3; }
  return val;
}

extern "C" __global__ void __launch_bounds__(256)
stochpool_kernel(const float* __restrict__ x, float* __restrict__ out,
                 int nquad) {
  int t = blockIdx.x * 256 + threadIdx.x;
  if (t >= nquad) return;
  // t = (bc*112 + i)*28 + jq ; 4 windows at j = 4*jq .. 4*jq+3
  uint32_t ut = (uint32_t)t;
  uint32_t jq = ut % 28u;
  uint32_t r  = ut / 28u;        // bc*112 + i
  uint32_t i  = r % OW;
  uint32_t bc = r / OW;
  uint32_t j  = jq * 4u;

  const float* base =
      x + ((size_t)bc * 224u + (size_t)(2u * i)) * 224u + 2u * j;
  float4 a0 = *reinterpret_cast<const float4*>(base);
  float4 a1 = *reinterpret_cast<const float4*>(base + 4);
  float4 b0 = *reinterpret_cast<const float4*>(base + 224);
  float4 b1 = *reinterpret_cast<const float4*>(base + 228);

  uint32_t wid = r * OW + j;     // flat window index (== output index, %4==0)
  float o0 = pool_window(a0.x, a0.y, b0.x, b0.y, (wid + 0u) * 4u);
  float o1 = pool_window(a0.z, a0.w, b0.z, b0.w, (wid + 1u) * 4u);
  float o2 = pool_window(a1.x, a1.y, b1.x, b1.y, (wid + 2u) * 4u);
  float o3 = pool_window(a1.z, a1.w, b1.z, b1.w, (wid + 3u) * 4u);

  *reinterpret_cast<float4*>(out + wid) = make_float4(o0, o1, o2, o3);
}

extern "C" void kernel_launch(void* const* d_in, const int* in_sizes, int n_in,
                              void* d_out, int out_size, void* d_ws, size_t ws_size,
                              hipStream_t stream) {
  const float* x = (const float*)d_in[0];
  float* out = (float*)d_out;
  int nquad = out_size / 4;  // 4,816,896 window-quads
  int blocks = (nquad + 255) / 256;
  stochpool_kernel<<<blocks, 256, 0, stream>>>(x, out, nquad);
}